// Round 3
// baseline (130.670 us; speedup 1.0000x reference)
//
#include <hip/hip_runtime.h>
#include <hip/hip_fp16.h>

#define BB_ 8
#define VV_ 5023
#define FF_ 9976
#define HH_ 512

static constexpr long long OUT_UV   = 0;                                   // uvcoords_images (B,3,H,H)
static constexpr long long OUT_POS  = OUT_UV   + (long long)BB_*3*HH_*HH_; // pos_mask        (B,1,H,H)
static constexpr long long OUT_GRID = OUT_POS  + (long long)BB_*HH_*HH_;   // grid            (B,H,H,2)
static constexpr long long OUT_N    = OUT_GRID + (long long)BB_*HH_*HH_*2; // normals         (B,V,3)
static constexpr long long OUT_NIMG = OUT_N    + (long long)BB_*VV_*3;     // normal_images   (B,3,H,H)
static constexpr long long OUT_TN   = OUT_NIMG + (long long)BB_*3*HH_*HH_; // t_normals       (B,V,3)

__device__ inline float pack_h2(float a, float b) {
    union { float f; __half2 h; } u;
    u.h = __halves2half2(__float2half_rn(a), __float2half_rn(b));
    return u.f;
}
__device__ inline float2 unpack_h2(float w) {
    union { float f; __half2 h; } u; u.f = w;
    return __half22float2(u.h);
}

// ---------------------------------------------------------------------------
// K1: one face normal per (b, mesh, f). All three reference scatter-adds equal
// cross(v1-v0, v2-v0). Keep z+10 before differencing to match ref rounding.
// ---------------------------------------------------------------------------
__global__ __launch_bounds__(256) void facenorm_k(const float* __restrict__ verts,
                                                  const float* __restrict__ tverts,
                                                  const int*   __restrict__ faces,
                                                  float* __restrict__ fnorm) {
    int t = blockIdx.x * blockDim.x + threadIdx.x;
    if (t >= BB_ * 2 * FF_) return;
    int bm = t / FF_;
    int f  = t - bm * FF_;
    int m  = bm & 1;
    int b  = bm >> 1;

    const float* vb = (m ? tverts : verts) + (long long)b * VV_ * 3;
    const float zoff = m ? 10.0f : 0.0f;

    int i0 = faces[f*3+0], i1 = faces[f*3+1], i2 = faces[f*3+2];
    float v0x = vb[i0*3+0], v0y = vb[i0*3+1], v0z = vb[i0*3+2] + zoff;
    float v1x = vb[i1*3+0], v1y = vb[i1*3+1], v1z = vb[i1*3+2] + zoff;
    float v2x = vb[i2*3+0], v2y = vb[i2*3+1], v2z = vb[i2*3+2] + zoff;
    float ax = v1x - v0x, ay = v1y - v0y, az = v1z - v0z;
    float bx = v2x - v0x, by = v2y - v0y, bz = v2z - v0z;
    fnorm[(long long)t*3+0] = ay * bz - az * by;
    fnorm[(long long)t*3+1] = az * bx - ax * bz;
    fnorm[(long long)t*3+2] = ax * by - ay * bx;
}

// ---------------------------------------------------------------------------
// K2: scatter. One thread per (face-instance, corner): 3 atomics into the
// L2-resident accumulator (964 KB). High grid parallelism hides latency.
// ---------------------------------------------------------------------------
__global__ __launch_bounds__(256) void scatter_k(const int*   __restrict__ faces,
                                                 const float* __restrict__ fnorm,
                                                 float* __restrict__ acc) {
    int t = blockIdx.x * blockDim.x + threadIdx.x;
    if (t >= BB_ * 2 * FF_ * 3) return;
    int g = t / 3;                 // face instance (bm*F + f)
    int k = t - g * 3;             // corner
    int bm = g / FF_;
    int f  = g - bm * FF_;
    int vi = faces[f*3 + k];

    float nx = fnorm[(long long)g*3+0];
    float ny = fnorm[(long long)g*3+1];
    float nz = fnorm[(long long)g*3+2];

    float* base = acc + ((long long)bm * VV_ + vi) * 3;
    atomicAdd(base + 0, nx);
    atomicAdd(base + 1, ny);
    atomicAdd(base + 2, nz);
}

// ---------------------------------------------------------------------------
// K3: normalize accumulated normals -> normals / t_normals outputs (fp32).
// ---------------------------------------------------------------------------
__global__ void merge_norm(const float* __restrict__ acc,
                           float* __restrict__ outN, float* __restrict__ outTN) {
    int idx = blockIdx.x * blockDim.x + threadIdx.x;   // over B*V
    if (idx >= BB_ * VV_) return;
    int b = idx / VV_;
    int v = idx - b * VV_;
    #pragma unroll
    for (int m = 0; m < 2; ++m) {
        const float* p = acc + ((long long)(b*2 + m) * VV_ + v) * 3;
        float x = p[0], y = p[1], z = p[2];
        float inv = 1.0f / fmaxf(sqrtf(x*x + y*y + z*z), 1e-6f);
        float* o = (m ? outTN : outN) + (long long)idx * 3;
        o[0] = x * inv; o[1] = y * inv; o[2] = z * inv;
    }
}

// ---------------------------------------------------------------------------
// K4: build compact records.
//   uvrec[f]  (32 B): 9 uv halves (pre-scaled), batch-independent -> 320 KB
//   nrec[b,f] (32 B): tnz0..2 fp32 (hard-threshold path!) + 9 normal halves
// Both L2-resident (2.9 MB total) -> raster gathers become L2 hits.
// ---------------------------------------------------------------------------
__global__ void build_recs(const int*   __restrict__ faces,
                           const float* __restrict__ uvc,
                           const float* __restrict__ outN,
                           const float* __restrict__ outTN,
                           float4* __restrict__ uvrec,
                           float4* __restrict__ nrec) {
    int t = blockIdx.x * blockDim.x + threadIdx.x;
    if (t >= BB_ * FF_) return;
    int b = t / FF_;
    int f = t - b * FF_;
    int ia = faces[f*3+0], ib = faces[f*3+1], ic = faces[f*3+2];

    const float* nb = outN  + (long long)b * VV_ * 3;
    const float* tb = outTN + (long long)b * VV_ * 3;
    float nax = nb[ia*3+0], nay = nb[ia*3+1], naz = nb[ia*3+2];
    float nbx = nb[ib*3+0], nby = nb[ib*3+1], nbz = nb[ib*3+2];
    float ncx = nb[ic*3+0], ncy = nb[ic*3+1], ncz = nb[ic*3+2];
    float ta = tb[ia*3+2], tbv = tb[ib*3+2], tc = tb[ic*3+2];

    nrec[(long long)t*2+0] = make_float4(ta, tbv, tc, pack_h2(ncz, 0.f));
    nrec[(long long)t*2+1] = make_float4(pack_h2(nax, nay), pack_h2(naz, nbx),
                                         pack_h2(nby, nbz), pack_h2(ncx, ncy));

    if (b == 0) {
        const float* u = uvc + (long long)f * 9;
        float r0 = u[0]*0.5f+0.5f, r1 = u[1]*0.5f+0.5f, r2 = u[2]*0.5f+0.5f;
        float r3 = u[3]*0.5f+0.5f, r4 = u[4]*0.5f+0.5f, r5 = u[5]*0.5f+0.5f;
        float r6 = u[6]*0.5f+0.5f, r7 = u[7]*0.5f+0.5f, r8 = u[8]*0.5f+0.5f;
        uvrec[(long long)f*2+0] = make_float4(pack_h2(r0,r1), pack_h2(r2,r3),
                                              pack_h2(r4,r5), pack_h2(r6,r7));
        uvrec[(long long)f*2+1] = make_float4(pack_h2(r8,0.f), 0.f, 0.f, 0.f);
    }
}

// ---------------------------------------------------------------------------
// K5: raster. Per hit pixel: 1 line from uvrec + 1 line from nrec (L2-hit)
// + coalesced p2f/bary streams + coalesced writes.
// ---------------------------------------------------------------------------
__global__ __launch_bounds__(256) void raster3(const int*    __restrict__ p2f,
                                               const float*  __restrict__ bary,
                                               const float4* __restrict__ uvrec,
                                               const float4* __restrict__ nrec,
                                               float* __restrict__ out) {
    int pix = blockIdx.x * blockDim.x + threadIdx.x;
    const int NPIX = BB_ * HH_ * HH_;
    if (pix >= NPIX) return;
    int b  = pix >> 18;              // H*H = 2^18
    int yx = pix & (HH_*HH_ - 1);

    int pf = p2f[pix];
    float uv0 = 0.f, uv1 = 0.f, uv2 = 0.f;
    float n0 = 0.f, n1 = 0.f, n2 = 0.f;
    float pm = 0.f;

    if (pf >= 0) {
        float w0 = bary[(long long)pix*3+0], w1 = bary[(long long)pix*3+1], w2 = bary[(long long)pix*3+2];
        int bb = pf / FF_;
        int ff = pf - bb * FF_;

        float4 U0 = uvrec[(long long)ff*2+0];
        float  U8 = ((const float*)uvrec)[(long long)ff*8+4];
        float2 u01 = unpack_h2(U0.x), u23 = unpack_h2(U0.y);
        float2 u45 = unpack_h2(U0.z), u67 = unpack_h2(U0.w);
        float2 u8p = unpack_h2(U8);

        float4 A  = nrec[(long long)pf*2+0];
        float4 Bq = nrec[(long long)pf*2+1];
        float2 m01 = unpack_h2(Bq.x), m23 = unpack_h2(Bq.y);
        float2 m45 = unpack_h2(Bq.z), m67 = unpack_h2(Bq.w);
        float2 m8p = unpack_h2(A.w);

        uv0 = w0*u01.x + w1*u23.y + w2*u67.x;
        uv1 = w0*u01.y + w1*u45.x + w2*u67.y;
        uv2 = w0*u23.x + w1*u45.y + w2*u8p.x;

        n0 = w0*m01.x + w1*m23.y + w2*m67.x;
        n1 = w0*m01.y + w1*m45.x + w2*m67.y;
        n2 = w0*m23.x + w1*m45.y + w2*m8p.x;

        float tnz = w0*A.x + w1*A.y + w2*A.z;   // fp32 path: hard threshold
        pm = (tnz < -0.05f) ? 1.0f : 0.0f;
    }

    const long long HW = (long long)HH_ * HH_;
    out[OUT_UV + ((long long)(b*3+0))*HW + yx] = uv0;
    out[OUT_UV + ((long long)(b*3+1))*HW + yx] = uv1;
    out[OUT_UV + ((long long)(b*3+2))*HW + yx] = uv2;
    out[OUT_POS + (long long)b*HW + yx] = pm;
    ((float2*)(out + OUT_GRID))[(long long)b*HW + yx] = make_float2(uv0, uv1);
    out[OUT_NIMG + ((long long)(b*3+0))*HW + yx] = n0;
    out[OUT_NIMG + ((long long)(b*3+1))*HW + yx] = n1;
    out[OUT_NIMG + ((long long)(b*3+2))*HW + yx] = n2;
}

extern "C" void kernel_launch(void* const* d_in, const int* in_sizes, int n_in,
                              void* d_out, int out_size, void* d_ws, size_t ws_size,
                              hipStream_t stream) {
    const float* vertices  = (const float*)d_in[0];
    const float* tvertices = (const float*)d_in[1];
    const float* face_uvc  = (const float*)d_in[3];
    const float* bary      = (const float*)d_in[4];
    const int*   faces     = (const int*)d_in[5];
    const int*   p2f       = (const int*)d_in[6];

    float* out = (float*)d_out;

    // ws layout: acc | fnorm | uvrec | nrec   (~5.8 MB total)
    float*  acc   = (float*)d_ws;                                   // B*2*V*3
    float*  fnorm = acc + (size_t)BB_*2*VV_*3;                      // B*2*F*3
    float4* uvrec = (float4*)(fnorm + (size_t)BB_*2*FF_*3);         // F*2 float4
    float4* nrec  = uvrec + (size_t)FF_*2;                          // B*F*2 float4

    hipMemsetAsync(acc, 0, (size_t)BB_*2*VV_*3*sizeof(float), stream);

    {
        int n = BB_ * 2 * FF_;
        facenorm_k<<<(n + 255) / 256, 256, 0, stream>>>(vertices, tvertices, faces, fnorm);
    }
    {
        int n = BB_ * 2 * FF_ * 3;
        scatter_k<<<(n + 255) / 256, 256, 0, stream>>>(faces, fnorm, acc);
    }
    {
        int n = BB_ * VV_;
        merge_norm<<<(n + 255) / 256, 256, 0, stream>>>(acc, out + OUT_N, out + OUT_TN);
    }
    {
        int n = BB_ * FF_;
        build_recs<<<(n + 255) / 256, 256, 0, stream>>>(faces, face_uvc, out + OUT_N, out + OUT_TN, uvrec, nrec);
    }
    {
        int n = BB_ * HH_ * HH_;
        raster3<<<(n + 255) / 256, 256, 0, stream>>>(p2f, bary, uvrec, nrec, out);
    }
}

// Round 4
// 77.465 us; speedup vs baseline: 1.6868x; 1.6868x over previous
//
#include <hip/hip_runtime.h>
#include <hip/hip_fp16.h>

#define BB_ 8
#define VV_ 5023
#define FF_ 9976
#define HH_ 512

static constexpr long long OUT_UV   = 0;                                   // uvcoords_images (B,3,H,H)
static constexpr long long OUT_POS  = OUT_UV   + (long long)BB_*3*HH_*HH_; // pos_mask        (B,1,H,H)
static constexpr long long OUT_GRID = OUT_POS  + (long long)BB_*HH_*HH_;   // grid            (B,H,H,2)
static constexpr long long OUT_N    = OUT_GRID + (long long)BB_*HH_*HH_*2; // normals         (B,V,3)
static constexpr long long OUT_NIMG = OUT_N    + (long long)BB_*VV_*3;     // normal_images   (B,3,H,H)
static constexpr long long OUT_TN   = OUT_NIMG + (long long)BB_*3*HH_*HH_; // t_normals       (B,V,3)

__device__ inline float pack_h2(float a, float b) {
    union { float f; __half2 h; } u;
    u.h = __halves2half2(__float2half_rn(a), __float2half_rn(b));
    return u.f;
}
__device__ inline float2 unpack_h2(float w) {
    union { float f; __half2 h; } u; u.f = w;
    return __half22float2(u.h);
}

// ---------------------------------------------------------------------------
// K1: one face normal per (b, mesh, f); bm==0 threads also count vertex
// degrees (int atomics, 30K total - cheap). All three reference scatter-adds
// equal cross(v1-v0, v2-v0); z+10 applied before differencing.
// ---------------------------------------------------------------------------
__global__ __launch_bounds__(256) void facenorm_k(const float* __restrict__ verts,
                                                  const float* __restrict__ tverts,
                                                  const int*   __restrict__ faces,
                                                  float* __restrict__ fnorm,
                                                  int*   __restrict__ counts) {
    int t = blockIdx.x * blockDim.x + threadIdx.x;
    if (t >= BB_ * 2 * FF_) return;
    int bm = t / FF_;
    int f  = t - bm * FF_;
    int m  = bm & 1;
    int b  = bm >> 1;

    const float* vb = (m ? tverts : verts) + (long long)b * VV_ * 3;
    const float zoff = m ? 10.0f : 0.0f;

    int i0 = faces[f*3+0], i1 = faces[f*3+1], i2 = faces[f*3+2];
    float v0x = vb[i0*3+0], v0y = vb[i0*3+1], v0z = vb[i0*3+2] + zoff;
    float v1x = vb[i1*3+0], v1y = vb[i1*3+1], v1z = vb[i1*3+2] + zoff;
    float v2x = vb[i2*3+0], v2y = vb[i2*3+1], v2z = vb[i2*3+2] + zoff;
    float ax = v1x - v0x, ay = v1y - v0y, az = v1z - v0z;
    float bx = v2x - v0x, by = v2y - v0y, bz = v2z - v0z;
    fnorm[(long long)t*3+0] = ay * bz - az * by;
    fnorm[(long long)t*3+1] = az * bx - ax * bz;
    fnorm[(long long)t*3+2] = ax * by - ay * bx;

    if (bm == 0) {
        atomicAdd(&counts[i0], 1);
        atomicAdd(&counts[i1], 1);
        atomicAdd(&counts[i2], 1);
    }
}

// ---------------------------------------------------------------------------
// K2: single-block exclusive scan over counts[V] -> offsets[V+1]; also
// initializes cursor[] = offsets[] for the fill pass.
// ---------------------------------------------------------------------------
__global__ __launch_bounds__(256) void scan_k(const int* __restrict__ counts,
                                              int* __restrict__ offsets,
                                              int* __restrict__ cursor) {
    __shared__ int sums[256];
    const int SEG = (VV_ + 255) / 256;   // 20
    int tid = threadIdx.x;

    int local[SEG];
    int s = 0;
    #pragma unroll
    for (int j = 0; j < SEG; ++j) {
        int v = tid * SEG + j;
        int c = (v < VV_) ? counts[v] : 0;
        local[j] = s;                     // exclusive within segment
        s += c;
    }
    sums[tid] = s;
    __syncthreads();
    for (int st = 1; st < 256; st <<= 1) {
        int add = (tid >= st) ? sums[tid - st] : 0;
        __syncthreads();
        sums[tid] += add;
        __syncthreads();
    }
    int base = (tid == 0) ? 0 : sums[tid - 1];
    #pragma unroll
    for (int j = 0; j < SEG; ++j) {
        int v = tid * SEG + j;
        if (v < VV_) {
            int o = base + local[j];
            offsets[v] = o;
            cursor[v]  = o;
        }
    }
    if (tid == 0) offsets[VV_] = FF_ * 3;
}

// ---------------------------------------------------------------------------
// K3: fill adjacency list: for each face-corner, claim a slot under its
// vertex and record the face id. (30K int atomics.)
// ---------------------------------------------------------------------------
__global__ __launch_bounds__(256) void fill_k(const int* __restrict__ faces,
                                              int* __restrict__ cursor,
                                              int* __restrict__ list) {
    int i = blockIdx.x * blockDim.x + threadIdx.x;
    if (i >= FF_ * 3) return;
    int v = faces[i];
    int slot = atomicAdd(&cursor[v], 1);
    list[slot] = i / 3;   // face id
}

// ---------------------------------------------------------------------------
// K4: gather. One thread per (bm, v): sum adjacent face normals from the
// L2-resident fnorm buffer, normalize, write outputs. No float atomics.
// ---------------------------------------------------------------------------
__global__ __launch_bounds__(256) void gather_k(const int* __restrict__ offsets,
                                                const int* __restrict__ list,
                                                const float* __restrict__ fnorm,
                                                float* __restrict__ outN,
                                                float* __restrict__ outTN) {
    int t = blockIdx.x * blockDim.x + threadIdx.x;
    if (t >= BB_ * 2 * VV_) return;
    int bm = t / VV_;
    int v  = t - bm * VV_;
    int o0 = offsets[v], o1 = offsets[v + 1];
    const float* fb = fnorm + (long long)bm * FF_ * 3;
    float x = 0.f, y = 0.f, z = 0.f;
    for (int j = o0; j < o1; ++j) {
        int f = list[j];
        x += fb[f*3+0];
        y += fb[f*3+1];
        z += fb[f*3+2];
    }
    float inv = 1.0f / fmaxf(sqrtf(x*x + y*y + z*z), 1e-6f);
    float* o = ((bm & 1) ? outTN : outN) + ((long long)(bm >> 1) * VV_ + v) * 3;
    o[0] = x * inv; o[1] = y * inv; o[2] = z * inv;
}

// ---------------------------------------------------------------------------
// K5: build compact records.
//   uvrec[f]  (32 B): 9 uv halves (pre-scaled), batch-independent -> 320 KB
//   nrec[b,f] (32 B): tnz0..2 fp32 (hard-threshold path!) + 9 normal halves
// Both L2-resident (2.9 MB) -> raster gathers are L2 hits.
// ---------------------------------------------------------------------------
__global__ void build_recs(const int*   __restrict__ faces,
                           const float* __restrict__ uvc,
                           const float* __restrict__ outN,
                           const float* __restrict__ outTN,
                           float4* __restrict__ uvrec,
                           float4* __restrict__ nrec) {
    int t = blockIdx.x * blockDim.x + threadIdx.x;
    if (t >= BB_ * FF_) return;
    int b = t / FF_;
    int f = t - b * FF_;
    int ia = faces[f*3+0], ib = faces[f*3+1], ic = faces[f*3+2];

    const float* nb = outN  + (long long)b * VV_ * 3;
    const float* tb = outTN + (long long)b * VV_ * 3;
    float nax = nb[ia*3+0], nay = nb[ia*3+1], naz = nb[ia*3+2];
    float nbx = nb[ib*3+0], nby = nb[ib*3+1], nbz = nb[ib*3+2];
    float ncx = nb[ic*3+0], ncy = nb[ic*3+1], ncz = nb[ic*3+2];
    float ta = tb[ia*3+2], tbv = tb[ib*3+2], tc = tb[ic*3+2];

    nrec[(long long)t*2+0] = make_float4(ta, tbv, tc, pack_h2(ncz, 0.f));
    nrec[(long long)t*2+1] = make_float4(pack_h2(nax, nay), pack_h2(naz, nbx),
                                         pack_h2(nby, nbz), pack_h2(ncx, ncy));

    if (b == 0) {
        const float* u = uvc + (long long)f * 9;
        float r0 = u[0]*0.5f+0.5f, r1 = u[1]*0.5f+0.5f, r2 = u[2]*0.5f+0.5f;
        float r3 = u[3]*0.5f+0.5f, r4 = u[4]*0.5f+0.5f, r5 = u[5]*0.5f+0.5f;
        float r6 = u[6]*0.5f+0.5f, r7 = u[7]*0.5f+0.5f, r8 = u[8]*0.5f+0.5f;
        uvrec[(long long)f*2+0] = make_float4(pack_h2(r0,r1), pack_h2(r2,r3),
                                              pack_h2(r4,r5), pack_h2(r6,r7));
        uvrec[(long long)f*2+1] = make_float4(pack_h2(r8,0.f), 0.f, 0.f, 0.f);
    }
}

// ---------------------------------------------------------------------------
// K6: raster. Per hit pixel: 1 line from uvrec + 2 lines from nrec (L2-hit)
// + coalesced p2f/bary streams + coalesced writes.
// ---------------------------------------------------------------------------
__global__ __launch_bounds__(256) void raster3(const int*    __restrict__ p2f,
                                               const float*  __restrict__ bary,
                                               const float4* __restrict__ uvrec,
                                               const float4* __restrict__ nrec,
                                               float* __restrict__ out) {
    int pix = blockIdx.x * blockDim.x + threadIdx.x;
    const int NPIX = BB_ * HH_ * HH_;
    if (pix >= NPIX) return;
    int b  = pix >> 18;              // H*H = 2^18
    int yx = pix & (HH_*HH_ - 1);

    int pf = p2f[pix];
    float uv0 = 0.f, uv1 = 0.f, uv2 = 0.f;
    float n0 = 0.f, n1 = 0.f, n2 = 0.f;
    float pm = 0.f;

    if (pf >= 0) {
        float w0 = bary[(long long)pix*3+0], w1 = bary[(long long)pix*3+1], w2 = bary[(long long)pix*3+2];
        int bb = pf / FF_;
        int ff = pf - bb * FF_;

        float4 U0 = uvrec[(long long)ff*2+0];
        float  U8 = ((const float*)uvrec)[(long long)ff*8+4];
        float2 u01 = unpack_h2(U0.x), u23 = unpack_h2(U0.y);
        float2 u45 = unpack_h2(U0.z), u67 = unpack_h2(U0.w);
        float2 u8p = unpack_h2(U8);

        float4 A  = nrec[(long long)pf*2+0];
        float4 Bq = nrec[(long long)pf*2+1];
        float2 m01 = unpack_h2(Bq.x), m23 = unpack_h2(Bq.y);
        float2 m45 = unpack_h2(Bq.z), m67 = unpack_h2(Bq.w);
        float2 m8p = unpack_h2(A.w);

        uv0 = w0*u01.x + w1*u23.y + w2*u67.x;
        uv1 = w0*u01.y + w1*u45.x + w2*u67.y;
        uv2 = w0*u23.x + w1*u45.y + w2*u8p.x;

        n0 = w0*m01.x + w1*m23.y + w2*m67.x;
        n1 = w0*m01.y + w1*m45.x + w2*m67.y;
        n2 = w0*m23.x + w1*m45.y + w2*m8p.x;

        float tnz = w0*A.x + w1*A.y + w2*A.z;   // fp32 path: hard threshold
        pm = (tnz < -0.05f) ? 1.0f : 0.0f;
    }

    const long long HW = (long long)HH_ * HH_;
    out[OUT_UV + ((long long)(b*3+0))*HW + yx] = uv0;
    out[OUT_UV + ((long long)(b*3+1))*HW + yx] = uv1;
    out[OUT_UV + ((long long)(b*3+2))*HW + yx] = uv2;
    out[OUT_POS + (long long)b*HW + yx] = pm;
    ((float2*)(out + OUT_GRID))[(long long)b*HW + yx] = make_float2(uv0, uv1);
    out[OUT_NIMG + ((long long)(b*3+0))*HW + yx] = n0;
    out[OUT_NIMG + ((long long)(b*3+1))*HW + yx] = n1;
    out[OUT_NIMG + ((long long)(b*3+2))*HW + yx] = n2;
}

extern "C" void kernel_launch(void* const* d_in, const int* in_sizes, int n_in,
                              void* d_out, int out_size, void* d_ws, size_t ws_size,
                              hipStream_t stream) {
    const float* vertices  = (const float*)d_in[0];
    const float* tvertices = (const float*)d_in[1];
    const float* face_uvc  = (const float*)d_in[3];
    const float* bary      = (const float*)d_in[4];
    const int*   faces     = (const int*)d_in[5];
    const int*   p2f       = (const int*)d_in[6];

    float* out = (float*)d_out;

    // ws layout (16B-aligned first): uvrec | nrec | fnorm | counts | offsets | cursor | list
    float4* uvrec   = (float4*)d_ws;                                  // F*2
    float4* nrec    = uvrec + (size_t)FF_*2;                          // B*F*2
    float*  fnorm   = (float*)(nrec + (size_t)BB_*FF_*2);             // B*2*F*3
    int*    counts  = (int*)(fnorm + (size_t)BB_*2*FF_*3);            // V
    int*    offsets = counts + VV_;                                   // V+1
    int*    cursor  = offsets + VV_ + 1;                              // V
    int*    list    = cursor + VV_;                                   // F*3

    hipMemsetAsync(counts, 0, (size_t)VV_ * sizeof(int), stream);

    {
        int n = BB_ * 2 * FF_;
        facenorm_k<<<(n + 255) / 256, 256, 0, stream>>>(vertices, tvertices, faces, fnorm, counts);
    }
    scan_k<<<1, 256, 0, stream>>>(counts, offsets, cursor);
    {
        int n = FF_ * 3;
        fill_k<<<(n + 255) / 256, 256, 0, stream>>>(faces, cursor, list);
    }
    {
        int n = BB_ * 2 * VV_;
        gather_k<<<(n + 255) / 256, 256, 0, stream>>>(offsets, list, fnorm, out + OUT_N, out + OUT_TN);
    }
    {
        int n = BB_ * FF_;
        build_recs<<<(n + 255) / 256, 256, 0, stream>>>(faces, face_uvc, out + OUT_N, out + OUT_TN, uvrec, nrec);
    }
    {
        int n = BB_ * HH_ * HH_;
        raster3<<<(n + 255) / 256, 256, 0, stream>>>(p2f, bary, uvrec, nrec, out);
    }
}

// Round 5
// 75.197 us; speedup vs baseline: 1.7377x; 1.0302x over previous
//
#include <hip/hip_runtime.h>
#include <hip/hip_fp16.h>

#define BB_ 8
#define VV_ 5023
#define FF_ 9976
#define HH_ 512

static constexpr long long OUT_UV   = 0;                                   // uvcoords_images (B,3,H,H)
static constexpr long long OUT_POS  = OUT_UV   + (long long)BB_*3*HH_*HH_; // pos_mask        (B,1,H,H)
static constexpr long long OUT_GRID = OUT_POS  + (long long)BB_*HH_*HH_;   // grid            (B,H,H,2)
static constexpr long long OUT_N    = OUT_GRID + (long long)BB_*HH_*HH_*2; // normals         (B,V,3)
static constexpr long long OUT_NIMG = OUT_N    + (long long)BB_*VV_*3;     // normal_images   (B,3,H,H)
static constexpr long long OUT_TN   = OUT_NIMG + (long long)BB_*3*HH_*HH_; // t_normals       (B,V,3)

__device__ inline float pack_h2(float a, float b) {
    union { float f; __half2 h; } u;
    u.h = __halves2half2(__float2half_rn(a), __float2half_rn(b));
    return u.f;
}
__device__ inline float2 unpack_h2(float w) {
    union { float f; __half2 h; } u; u.f = w;
    return __half22float2(u.h);
}

// ---------------------------------------------------------------------------
// K1: one face normal per (b, mesh, f); bm==0 threads also count vertex
// degrees. All three reference scatter-adds equal cross(v1-v0, v2-v0).
// ---------------------------------------------------------------------------
__global__ __launch_bounds__(256) void facenorm_k(const float* __restrict__ verts,
                                                  const float* __restrict__ tverts,
                                                  const int*   __restrict__ faces,
                                                  float* __restrict__ fnorm,
                                                  int*   __restrict__ counts) {
    int t = blockIdx.x * blockDim.x + threadIdx.x;
    if (t >= BB_ * 2 * FF_) return;
    int bm = t / FF_;
    int f  = t - bm * FF_;
    int m  = bm & 1;
    int b  = bm >> 1;

    const float* vb = (m ? tverts : verts) + (long long)b * VV_ * 3;
    const float zoff = m ? 10.0f : 0.0f;

    int i0 = faces[f*3+0], i1 = faces[f*3+1], i2 = faces[f*3+2];
    float v0x = vb[i0*3+0], v0y = vb[i0*3+1], v0z = vb[i0*3+2] + zoff;
    float v1x = vb[i1*3+0], v1y = vb[i1*3+1], v1z = vb[i1*3+2] + zoff;
    float v2x = vb[i2*3+0], v2y = vb[i2*3+1], v2z = vb[i2*3+2] + zoff;
    float ax = v1x - v0x, ay = v1y - v0y, az = v1z - v0z;
    float bx = v2x - v0x, by = v2y - v0y, bz = v2z - v0z;
    fnorm[(long long)t*3+0] = ay * bz - az * by;
    fnorm[(long long)t*3+1] = az * bx - ax * bz;
    fnorm[(long long)t*3+2] = ax * by - ay * bx;

    if (bm == 0) {
        atomicAdd(&counts[i0], 1);
        atomicAdd(&counts[i1], 1);
        atomicAdd(&counts[i2], 1);
    }
}

// ---------------------------------------------------------------------------
// K2: single-block exclusive scan over counts[V] -> offsets[V+1] and cursor[].
// ---------------------------------------------------------------------------
__global__ __launch_bounds__(256) void scan_k(const int* __restrict__ counts,
                                              int* __restrict__ offsets,
                                              int* __restrict__ cursor) {
    __shared__ int sums[256];
    const int SEG = (VV_ + 255) / 256;   // 20
    int tid = threadIdx.x;

    int local[SEG];
    int s = 0;
    #pragma unroll
    for (int j = 0; j < SEG; ++j) {
        int v = tid * SEG + j;
        int c = (v < VV_) ? counts[v] : 0;
        local[j] = s;
        s += c;
    }
    sums[tid] = s;
    __syncthreads();
    for (int st = 1; st < 256; st <<= 1) {
        int add = (tid >= st) ? sums[tid - st] : 0;
        __syncthreads();
        sums[tid] += add;
        __syncthreads();
    }
    int base = (tid == 0) ? 0 : sums[tid - 1];
    #pragma unroll
    for (int j = 0; j < SEG; ++j) {
        int v = tid * SEG + j;
        if (v < VV_) {
            int o = base + local[j];
            offsets[v] = o;
            cursor[v]  = o;
        }
    }
    if (tid == 0) offsets[VV_] = FF_ * 3;
}

// ---------------------------------------------------------------------------
// K3: fill adjacency list (30K int atomics).
// ---------------------------------------------------------------------------
__global__ __launch_bounds__(256) void fill_k(const int* __restrict__ faces,
                                              int* __restrict__ cursor,
                                              int* __restrict__ list) {
    int i = blockIdx.x * blockDim.x + threadIdx.x;
    if (i >= FF_ * 3) return;
    int v = faces[i];
    int slot = atomicAdd(&cursor[v], 1);
    list[slot] = i / 3;
}

// ---------------------------------------------------------------------------
// K4: gather per (bm, v): sum adjacent face normals (L2-resident), normalize.
// ---------------------------------------------------------------------------
__global__ __launch_bounds__(256) void gather_k(const int* __restrict__ offsets,
                                                const int* __restrict__ list,
                                                const float* __restrict__ fnorm,
                                                float* __restrict__ outN,
                                                float* __restrict__ outTN) {
    int t = blockIdx.x * blockDim.x + threadIdx.x;
    if (t >= BB_ * 2 * VV_) return;
    int bm = t / VV_;
    int v  = t - bm * VV_;
    int o0 = offsets[v], o1 = offsets[v + 1];
    const float* fb = fnorm + (long long)bm * FF_ * 3;
    float x = 0.f, y = 0.f, z = 0.f;
    for (int j = o0; j < o1; ++j) {
        int f = list[j];
        x += fb[f*3+0];
        y += fb[f*3+1];
        z += fb[f*3+2];
    }
    float inv = 1.0f / fmaxf(sqrtf(x*x + y*y + z*z), 1e-6f);
    float* o = ((bm & 1) ? outTN : outN) + ((long long)(bm >> 1) * VV_ + v) * 3;
    o[0] = x * inv; o[1] = y * inv; o[2] = z * inv;
}

// ---------------------------------------------------------------------------
// K5: build compact records.
//   uvrec[f]  (32 B): 9 uv halves (pre-scaled)      -> 320 KB (L2)
//   nrec[b,f] (32 B): tnz0..2 fp32 + 9 normal halves -> 2.55 MB (L2)
// ---------------------------------------------------------------------------
__global__ void build_recs(const int*   __restrict__ faces,
                           const float* __restrict__ uvc,
                           const float* __restrict__ outN,
                           const float* __restrict__ outTN,
                           float4* __restrict__ uvrec,
                           float4* __restrict__ nrec) {
    int t = blockIdx.x * blockDim.x + threadIdx.x;
    if (t >= BB_ * FF_) return;
    int b = t / FF_;
    int f = t - b * FF_;
    int ia = faces[f*3+0], ib = faces[f*3+1], ic = faces[f*3+2];

    const float* nb = outN  + (long long)b * VV_ * 3;
    const float* tb = outTN + (long long)b * VV_ * 3;
    float nax = nb[ia*3+0], nay = nb[ia*3+1], naz = nb[ia*3+2];
    float nbx = nb[ib*3+0], nby = nb[ib*3+1], nbz = nb[ib*3+2];
    float ncx = nb[ic*3+0], ncy = nb[ic*3+1], ncz = nb[ic*3+2];
    float ta = tb[ia*3+2], tbv = tb[ib*3+2], tc = tb[ic*3+2];

    nrec[(long long)t*2+0] = make_float4(ta, tbv, tc, pack_h2(ncz, 0.f));
    nrec[(long long)t*2+1] = make_float4(pack_h2(nax, nay), pack_h2(naz, nbx),
                                         pack_h2(nby, nbz), pack_h2(ncx, ncy));

    if (b == 0) {
        const float* u = uvc + (long long)f * 9;
        float r0 = u[0]*0.5f+0.5f, r1 = u[1]*0.5f+0.5f, r2 = u[2]*0.5f+0.5f;
        float r3 = u[3]*0.5f+0.5f, r4 = u[4]*0.5f+0.5f, r5 = u[5]*0.5f+0.5f;
        float r6 = u[6]*0.5f+0.5f, r7 = u[7]*0.5f+0.5f, r8 = u[8]*0.5f+0.5f;
        uvrec[(long long)f*2+0] = make_float4(pack_h2(r0,r1), pack_h2(r2,r3),
                                              pack_h2(r4,r5), pack_h2(r6,r7));
        uvrec[(long long)f*2+1] = make_float4(pack_h2(r8,0.f), 0.f, 0.f, 0.f);
    }
}

// ---------------------------------------------------------------------------
// Per-pixel shade helper (inlined 4x -> 4 independent gather chains).
// ---------------------------------------------------------------------------
__device__ inline void shade(int pf, float w0, float w1, float w2,
                             const float4* __restrict__ uvrec,
                             const float4* __restrict__ nrec,
                             float& uv0, float& uv1, float& uv2,
                             float& n0, float& n1, float& n2, float& pm) {
    int pfs = pf < 0 ? 0 : pf;
    int bb = pfs / FF_;
    int ff = pfs - bb * FF_;

    float4 U0 = uvrec[(long long)ff*2+0];
    float  U8 = ((const float*)uvrec)[(long long)ff*8+4];
    float4 A  = nrec[(long long)pfs*2+0];
    float4 Bq = nrec[(long long)pfs*2+1];

    float2 u01 = unpack_h2(U0.x), u23 = unpack_h2(U0.y);
    float2 u45 = unpack_h2(U0.z), u67 = unpack_h2(U0.w);
    float2 u8p = unpack_h2(U8);
    float2 m01 = unpack_h2(Bq.x), m23 = unpack_h2(Bq.y);
    float2 m45 = unpack_h2(Bq.z), m67 = unpack_h2(Bq.w);
    float2 m8p = unpack_h2(A.w);

    uv0 = w0*u01.x + w1*u23.y + w2*u67.x;
    uv1 = w0*u01.y + w1*u45.x + w2*u67.y;
    uv2 = w0*u23.x + w1*u45.y + w2*u8p.x;
    n0  = w0*m01.x + w1*m23.y + w2*m67.x;
    n1  = w0*m01.y + w1*m45.x + w2*m67.y;
    n2  = w0*m23.x + w1*m45.y + w2*m8p.x;
    float tnz = w0*A.x + w1*A.y + w2*A.z;     // fp32: hard threshold path
    pm = (tnz < -0.05f) ? 1.0f : 0.0f;

    if (pf < 0) { uv0 = uv1 = uv2 = n0 = n1 = n2 = pm = 0.0f; }
}

// ---------------------------------------------------------------------------
// K6: raster, 4 consecutive pixels per thread.
//   streams: 1x int4 (p2f) + 3x float4 (bary) loads; 9x float4 stores.
//   gathers: 16 independent loads in flight (4 chains).
// ---------------------------------------------------------------------------
__global__ __launch_bounds__(256) void raster4(const int4*   __restrict__ p2f4,
                                               const float4* __restrict__ bary4,
                                               const float4* __restrict__ uvrec,
                                               const float4* __restrict__ nrec,
                                               float* __restrict__ out) {
    int t = blockIdx.x * blockDim.x + threadIdx.x;
    const int NQ = BB_ * HH_ * HH_ / 4;
    if (t >= NQ) return;
    int pix0 = t << 2;
    int b    = pix0 >> 18;              // H*H = 2^18; 4 consecutive pixels share b
    int yx0  = pix0 & (HH_*HH_ - 1);

    int4   pf = p2f4[t];
    float4 B0 = bary4[(long long)t*3+0];
    float4 B1 = bary4[(long long)t*3+1];
    float4 B2 = bary4[(long long)t*3+2];

    float uv0a, uv1a, uv2a, n0a, n1a, n2a, pma;
    float uv0b, uv1b, uv2b, n0b, n1b, n2b, pmb;
    float uv0c, uv1c, uv2c, n0c, n1c, n2c, pmc;
    float uv0d, uv1d, uv2d, n0d, n1d, n2d, pmd;

    shade(pf.x, B0.x, B0.y, B0.z, uvrec, nrec, uv0a, uv1a, uv2a, n0a, n1a, n2a, pma);
    shade(pf.y, B0.w, B1.x, B1.y, uvrec, nrec, uv0b, uv1b, uv2b, n0b, n1b, n2b, pmb);
    shade(pf.z, B1.z, B1.w, B2.x, uvrec, nrec, uv0c, uv1c, uv2c, n0c, n1c, n2c, pmc);
    shade(pf.w, B2.y, B2.z, B2.w, uvrec, nrec, uv0d, uv1d, uv2d, n0d, n1d, n2d, pmd);

    const long long HW = (long long)HH_ * HH_;
    *(float4*)(out + OUT_UV  + ((long long)(b*3+0))*HW + yx0) = make_float4(uv0a, uv0b, uv0c, uv0d);
    *(float4*)(out + OUT_UV  + ((long long)(b*3+1))*HW + yx0) = make_float4(uv1a, uv1b, uv1c, uv1d);
    *(float4*)(out + OUT_UV  + ((long long)(b*3+2))*HW + yx0) = make_float4(uv2a, uv2b, uv2c, uv2d);
    *(float4*)(out + OUT_POS + (long long)b*HW + yx0)         = make_float4(pma, pmb, pmc, pmd);
    float* gbase = out + OUT_GRID + ((long long)b*HW + yx0)*2;
    *(float4*)(gbase + 0) = make_float4(uv0a, uv1a, uv0b, uv1b);
    *(float4*)(gbase + 4) = make_float4(uv0c, uv1c, uv0d, uv1d);
    *(float4*)(out + OUT_NIMG + ((long long)(b*3+0))*HW + yx0) = make_float4(n0a, n0b, n0c, n0d);
    *(float4*)(out + OUT_NIMG + ((long long)(b*3+1))*HW + yx0) = make_float4(n1a, n1b, n1c, n1d);
    *(float4*)(out + OUT_NIMG + ((long long)(b*3+2))*HW + yx0) = make_float4(n2a, n2b, n2c, n2d);
}

extern "C" void kernel_launch(void* const* d_in, const int* in_sizes, int n_in,
                              void* d_out, int out_size, void* d_ws, size_t ws_size,
                              hipStream_t stream) {
    const float* vertices  = (const float*)d_in[0];
    const float* tvertices = (const float*)d_in[1];
    const float* face_uvc  = (const float*)d_in[3];
    const float* bary      = (const float*)d_in[4];
    const int*   faces     = (const int*)d_in[5];
    const int*   p2f       = (const int*)d_in[6];

    float* out = (float*)d_out;

    // ws layout (16B-aligned first): uvrec | nrec | fnorm | counts | offsets | cursor | list
    float4* uvrec   = (float4*)d_ws;                                  // F*2
    float4* nrec    = uvrec + (size_t)FF_*2;                          // B*F*2
    float*  fnorm   = (float*)(nrec + (size_t)BB_*FF_*2);             // B*2*F*3
    int*    counts  = (int*)(fnorm + (size_t)BB_*2*FF_*3);            // V
    int*    offsets = counts + VV_;                                   // V+1
    int*    cursor  = offsets + VV_ + 1;                              // V
    int*    list    = cursor + VV_;                                   // F*3

    hipMemsetAsync(counts, 0, (size_t)VV_ * sizeof(int), stream);

    {
        int n = BB_ * 2 * FF_;
        facenorm_k<<<(n + 255) / 256, 256, 0, stream>>>(vertices, tvertices, faces, fnorm, counts);
    }
    scan_k<<<1, 256, 0, stream>>>(counts, offsets, cursor);
    {
        int n = FF_ * 3;
        fill_k<<<(n + 255) / 256, 256, 0, stream>>>(faces, cursor, list);
    }
    {
        int n = BB_ * 2 * VV_;
        gather_k<<<(n + 255) / 256, 256, 0, stream>>>(offsets, list, fnorm, out + OUT_N, out + OUT_TN);
    }
    {
        int n = BB_ * FF_;
        build_recs<<<(n + 255) / 256, 256, 0, stream>>>(faces, face_uvc, out + OUT_N, out + OUT_TN, uvrec, nrec);
    }
    {
        int nq = BB_ * HH_ * HH_ / 4;
        raster4<<<(nq + 255) / 256, 256, 0, stream>>>((const int4*)p2f, (const float4*)bary,
                                                      uvrec, nrec, out);
    }
}